// Round 2
// baseline (317.430 us; speedup 1.0000x reference)
//
#include <hip/hip_runtime.h>
#include <math.h>

// Detector loss: N=65536 samples, G=7 (49 cells), A=3 anchors, C=2 classes.
// bbox_ : (N,15,7,7) predictions, channel 5a+0 = objectness(a), 5a+1..5a+4 = x,y,w,h
// bbox  : (N, 5,7,7) GT,          channel 0 = prob map,        1..4       = x,y,w,h
// cls_  : (N,2) logits; cls : (N,) labels in {1,2}
// out   : scalar fp32
//
// Round-2 structure: block-cooperative async staging (global_load_lds width=16),
// double-buffered 4-sample groups (31.4 KB LDS -> 5 blocks/CU), one sample per
// wave per iteration. Staging of group g+1 issues at top of iteration g and
// drains at the iteration-end barrier -> HBM/L3 latency hidden under compute.
// Argmax = 6 single-shuffle max rounds + ballot/ffs (half the old chain).
// Transcendentals cut 16 -> 7/sample (packed-lane log for coord/size, log1p CE).

static constexpr int GG  = 49;
static constexpr int PRD = 15 * GG;    // 735 dwords / pred sample
static constexpr int GTD = 5  * GG;    // 245 dwords / gt sample
static constexpr int SPG = 4;          // samples per group (16B-aligned chunks)
static constexpr int PRC = SPG * PRD;  // 2940 dwords / group
static constexpr int GTC = SPG * GTD;  // 980 dwords / group
static constexpr int PRB = PRC * 4;    // 11760 bytes (= 735 x 16, 16B aligned)
static constexpr int GTB = GTC * 4;    // 3920 bytes  (= 245 x 16, 16B aligned)

__global__ void zero_kernel(float* out) { if (threadIdx.x == 0) out[0] = 0.0f; }

__device__ __forceinline__ void gload16(const float* g, float* l) {
    // async global -> LDS, 16B/lane; LDS dest = uniform base + lane*16 (linear)
    __builtin_amdgcn_global_load_lds(
        (const __attribute__((address_space(1))) void*)g,
        (__attribute__((address_space(3))) void*)l, 16, 0, 0);
}

// Stage one 4-sample group: pr chunk (11760B) at buf[0..2939], gt chunk (3920B)
// at buf[2940..3919]. 12 + 4 wave-units of 1024B, split across the 4 waves.
__device__ __forceinline__ void stage_group(const float* __restrict__ prs,
                                            const float* __restrict__ gts,
                                            float* buf, int wslot, int lane) {
    #pragma unroll
    for (int u0 = 0; u0 < 3; ++u0) {               // 12 pr units, 3 per wave
        const int u   = wslot + 4 * u0;
        const int rem = PRB - (u << 10);           // u=11: 496B -> lanes 0..30
        if ((lane << 4) < rem)
            gload16(prs + (u << 8) + (lane << 2), buf + (u << 8));
    }
    {   const int u   = wslot;                     // 4 gt units, 1 per wave
        const int rem = GTB - (u << 10);           // u=3: 848B -> lanes 0..52
        if ((lane << 4) < rem)
            gload16(gts + (u << 8) + (lane << 2), buf + PRC + (u << 8));
    }
}

__global__ __launch_bounds__(256) void loss_kernel(
    const float* __restrict__ pr_all,     // bbox_
    const float* __restrict__ cls_logits, // cls_
    const float* __restrict__ gt_all,     // bbox
    const int*   __restrict__ cls_lbl,    // cls
    float* __restrict__ out, int N)
{
    const int lane  = threadIdx.x & 63;
    const int wslot = threadIdx.x >> 6;
    const float invG   = 1.0f / 7.0f;
    const float invN   = 1.0f / (float)N;
    const float invN49 = 1.0f / ((float)N * 49.0f);

    __shared__ float L[2][PRC + GTC];   // 2 x 15680 B = 31360 B -> 5 blocks/CU

    // block-contiguous group partition: 16384 groups / 2048 blocks = 8 each
    const int ngroups = N >> 2;
    const int per = (ngroups + gridDim.x - 1) / gridDim.x;
    const int gA  = blockIdx.x * per;
    const int gB  = min(gA + per, ngroups);

    float acc = 0.0f;
    int cur = 0;

    if (gA < gB)
        stage_group(pr_all + (size_t)gA * PRC, gt_all + (size_t)gA * GTC,
                    L[0], wslot, lane);
    __syncthreads();   // drains vmcnt(0): buffer 0 ready

    for (int g = gA; g < gB; ++g) {
        const int n = (g << 2) + wslot;            // this wave's sample

        // wave-uniform CE inputs: issue before next staging so their wait
        // doesn't have to drain the staging queue
        const float x0 = cls_logits[2 * n];
        const float x1 = cls_logits[2 * n + 1];
        const int   cl = cls_lbl[n];

        // prefetch next group into the other buffer (async, drains at barrier)
        if (g + 1 < gB)
            stage_group(pr_all + (size_t)(g + 1) * PRC,
                        gt_all + (size_t)(g + 1) * GTC,
                        L[cur ^ 1], wslot, lane);

        const float* Lp = L[cur];                  // pr chunk
        const float* Lg = L[cur] + PRC;            // gt chunk
        const int pb_ = wslot * PRD;               // this sample's pr base
        const int gb_ = wslot * GTD;               // this sample's gt base

        // ---- 1) GT prob map argmax: 6 max rounds + ballot (min-index ties) ----
        const float t = (lane < GG) ? Lg[gb_ + lane] : -1.0f; // sentinel loses
        float v = t;
        #pragma unroll
        for (int off = 32; off; off >>= 1) v = fmaxf(v, __shfl_xor(v, off));
        const unsigned long long eq = __ballot(t == v);
        const int m  = __ffsll(eq) - 1;            // wave-uniform, in [0,49)
        const int mi = m / 7, mj = m - mi * 7;
        const float jf = (float)mj, if_ = (float)mi;

        // ---- 2) cell-m GT box via uniform LDS broadcast reads ----
        const float g1v = Lg[gb_ +  49 + m];
        const float g2v = Lg[gb_ +  98 + m];
        const float g3v = Lg[gb_ + 147 + m];
        const float g4v = Lg[gb_ + 196 + m];

        const float tx  = (g1v + jf) * invG;
        const float ty  = (g2v + if_) * invG;
        const float tx1 = tx - g3v * 0.5f, tx2 = tx + g3v * 0.5f;
        const float ty1 = ty - g4v * 0.5f, ty2 = ty + g4v * 0.5f;
        const float tarea = (tx2 - tx1) * (ty2 - ty1);

        // ---- 3) IoU argmax over anchors (uniform on all lanes) ----
        int best = 0; float bestIoU = -1.0f;
        float px = 0.f, py = 0.f, pw = 0.f, ph = 0.f;
        #pragma unroll
        for (int a = 0; a < 3; a++) {
            const float c1 = Lp[pb_ + (5 * a + 1) * GG + m];
            const float c2 = Lp[pb_ + (5 * a + 2) * GG + m];
            const float c3 = Lp[pb_ + (5 * a + 3) * GG + m];
            const float c4 = Lp[pb_ + (5 * a + 4) * GG + m];
            const float ax  = (c1 + jf) * invG;
            const float ay  = (c2 + if_) * invG;
            const float ax1 = ax - c3 * 0.5f, ax2 = ax + c3 * 0.5f;
            const float ay1 = ay - c4 * 0.5f, ay2 = ay + c4 * 0.5f;
            float iw = fminf(ax2, tx2) - fmaxf(ax1, tx1); iw = fmaxf(iw, 0.0f);
            float ih = fminf(ay2, ty2) - fmaxf(ay1, ty1); ih = fmaxf(ih, 0.0f);
            const float inter = iw * ih;
            const float uni   = (ax2 - ax1) * (ay2 - ay1) + tarea - inter;
            const float iou   = inter / (uni + 1e-9f);
            if (iou > bestIoU) { bestIoU = iou; best = a; px = c1; py = c2; pw = c3; ph = c4; }
        }

        // ---- 4) prob_loss: 3x -log(1-p) + best-channel correction (4 trans) ----
        float s = 0.0f;
        if (lane < GG) {
            const float p0 = Lp[pb_ +           lane];
            const float p1 = Lp[pb_ + 5 * GG  + lane];
            const float p2 = Lp[pb_ + 10 * GG + lane];
            const float l0 = __logf(1.0f - p0);
            const float l1 = __logf(1.0f - p1);
            const float l2 = __logf(1.0f - p2);
            s = -(l0 + l1 + l2);
            const float pbv  = (best == 0) ? p0 : (best == 1) ? p1 : p2;
            const float l1pb = (best == 0) ? l0 : (best == 1) ? l1 : l2;
            s -= t * (__logf(pbv) - l1pb);
        }
        acc += s * invN49;

        // ---- 5) coord + size: 8 logs packed into ONE v_log_f32 on lanes 0-7.
        //         lanes: 0:px 1:1-px 2:py 3:1-py 4:pw 5:g3 6:ph 7:g4
        //         (combined through the end-of-kernel wave reduction) ----
        const float s0  = (lane < 4) ? ((lane < 2) ? px : py)
                                     : ((lane < 6) ? pw : ph);
        const float s1  = (lane < 4) ? (1.0f - s0)
                                     : ((lane < 6) ? g3v : g4v);
        const float la  = (lane & 1) ? s1 : s0;      // >0 on every lane
        const float Lv  = __logf(la);
        const float Lx  = __shfl_xor(Lv, 1);
        float contrib = 0.0f;
        if (lane < 4) {
            const float w = (lane < 2) ? ((lane & 1) ? 1.0f - g1v : g1v)
                                       : ((lane & 1) ? 1.0f - g2v : g2v);
            contrib = -w * Lv;                        // coord BCE terms
        } else if (lane == 4 || lane == 6) {
            contrib = fabsf(Lv - Lx);                 // size log-L1 terms
        }
        acc += contrib;

        // ---- 6) CE mean: lse = mx + log(1 + exp(-|x0-x1|)) (2 trans) ----
        if (lane == 5) {
            const float mx  = fmaxf(x0, x1);
            const float lse = mx + __logf(1.0f + __expf(-fabsf(x0 - x1)));
            const float lp  = ((cl == 1) ? x0 : x1) - lse;
            acc -= lp * invN;
        }

        __syncthreads();   // readers done + next buffer's staging drained
        cur ^= 1;
    }

    // ---- block reduction, one atomic per block ----
    #pragma unroll
    for (int off = 32; off; off >>= 1) acc += __shfl_xor(acc, off);
    __shared__ float wsum[4];
    if (lane == 0) wsum[wslot] = acc;
    __syncthreads();
    if (threadIdx.x == 0) {
        atomicAdd(out, wsum[0] + wsum[1] + wsum[2] + wsum[3]);
    }
}

extern "C" void kernel_launch(void* const* d_in, const int* in_sizes, int n_in,
                              void* d_out, int out_size, void* d_ws, size_t ws_size,
                              hipStream_t stream) {
    const float* bbox_p = (const float*)d_in[0];   // (N,15,7,7)
    const float* cls_p  = (const float*)d_in[1];   // (N,2)
    const float* bbox_g = (const float*)d_in[2];   // (N,5,7,7)
    const int*   cls_l  = (const int*)d_in[3];     // (N,)
    float* out = (float*)d_out;
    const int N = in_sizes[3];

    hipLaunchKernelGGL(zero_kernel, dim3(1), dim3(64), 0, stream, out);
    // 2048 blocks x 4 waves; each block: 8 double-buffered 4-sample groups.
    hipLaunchKernelGGL(loss_kernel, dim3(2048), dim3(256), 0, stream,
                       bbox_p, cls_p, bbox_g, cls_l, out, N);
}

// Round 3
// 296.701 us; speedup vs baseline: 1.0699x; 1.0699x over previous
//
#include <hip/hip_runtime.h>
#include <math.h>

// Detector loss: N=65536 samples, G=7 (49 cells), A=3 anchors, C=2 classes.
// bbox_ : (N,15,7,7) predictions, channel 5a+0 = objectness(a), 5a+1..5a+4 = x,y,w,h
// bbox  : (N, 5,7,7) GT,          channel 0 = prob map,        1..4       = x,y,w,h
// cls_  : (N,2) logits; cls : (N,) labels in {1,2}
// out   : scalar fp32
//
// Round-3 experiment: NON-TEMPORAL input reads. Theory: the preceding 735 MB
// harness fill leaves L3/L2 full of dirty lines; a normal streaming read of
// 258 MB forces dirty evictions -> the loss kernel pays the fill's writeback
// debt (invisible in its FETCH_SIZE), which pinned R0/R1/R2 at ~110 us despite
// disjoint structures. nt loads don't allocate in L3 -> no forced writebacks.
// Structure otherwise: simplest proven form (per-wave LDS park, no in-loop
// barriers) + ballot argmax + packed-lane log epilogue.

static constexpr int GG  = 49;
static constexpr int PRD = 15 * GG;   // 735 dwords / pred sample
static constexpr int GTD = 5  * GG;   // 245 dwords / gt sample
static constexpr int GOF = 768;       // gt offset inside a wave's LDS slot
static constexpr int LPW = 1024;      // floats per wave slot (4 KB)

__global__ void zero_kernel(float* out) { if (threadIdx.x == 0) out[0] = 0.0f; }

__global__ __launch_bounds__(256) void loss_kernel(
    const float* __restrict__ pr_all,     // bbox_
    const float* __restrict__ cls_logits, // cls_
    const float* __restrict__ gt_all,     // bbox
    const int*   __restrict__ cls_lbl,    // cls
    float* __restrict__ out, int N)
{
    const int lane  = threadIdx.x & 63;
    const int wslot = threadIdx.x >> 6;
    const int wid   = blockIdx.x * (blockDim.x >> 6) + wslot;
    const int nwaves = gridDim.x * (blockDim.x >> 6);
    const float invG   = 1.0f / 7.0f;
    const float invN   = 1.0f / (float)N;
    const float invN49 = 1.0f / ((float)N * 49.0f);

    __shared__ float L[4][LPW];          // 16 KB/block -> 8 blocks/CU (thread cap)
    float* __restrict__ Lw = L[wslot];   // per-wave slot: pr at 0, gt at GOF

    float acc = 0.0f;

    for (int n = wid; n < N; n += nwaves) {
        const float* pr = pr_all + (size_t)n * PRD;
        const float* gt = gt_all + (size_t)n * GTD;

        // wave-uniform CE inputs (read once -> nt), issued early
        const float x0 = __builtin_nontemporal_load(cls_logits + 2 * n);
        const float x1 = __builtin_nontemporal_load(cls_logits + 2 * n + 1);
        const int   cl = __builtin_nontemporal_load(cls_lbl + n);

        // ---- 1) stream the whole sample: 16 independent coalesced nt loads ----
        float p[12];
        #pragma unroll
        for (int k = 0; k < 12; ++k) {
            int d = lane + 64 * k;
            if (d > PRD - 1) d = PRD - 1;          // tail clamp (k=11 only)
            p[k] = __builtin_nontemporal_load(pr + d);
        }
        float g[4];
        #pragma unroll
        for (int k = 0; k < 4; ++k) {
            int d = lane + 64 * k;
            if (d > GTD - 1) d = GTD - 1;          // tail clamp (k=3 only)
            g[k] = __builtin_nontemporal_load(gt + d);
        }

        // ---- 2) park in this wave's LDS slot (wave-synchronous, no barrier) ----
        #pragma unroll
        for (int k = 0; k < 12; ++k) {
            int d = lane + 64 * k;
            if (d > PRD - 1) d = PRD - 1;
            Lw[d] = p[k];
        }
        #pragma unroll
        for (int k = 0; k < 4; ++k) {
            int d = lane + 64 * k;
            if (d > GTD - 1) d = GTD - 1;
            Lw[GOF + d] = g[k];
        }
        asm volatile("s_waitcnt lgkmcnt(0)" ::: "memory");

        // ---- 3) GT prob argmax: 6 max rounds + ballot (min-index tie-break) ----
        const float t = (lane < GG) ? g[0] : -1.0f;  // sentinel loses (probs>=0.01)
        float v = t;
        #pragma unroll
        for (int off = 32; off; off >>= 1) v = fmaxf(v, __shfl_xor(v, off));
        const unsigned long long eq = __ballot(t == v);
        const int m  = __ffsll(eq) - 1;              // wave-uniform, in [0,49)
        const int mi = m / 7, mj = m - mi * 7;
        const float jf = (float)mj, if_ = (float)mi;

        // ---- 4) cell-m GT box via uniform LDS broadcast reads ----
        const float g1v = Lw[GOF +  49 + m];
        const float g2v = Lw[GOF +  98 + m];
        const float g3v = Lw[GOF + 147 + m];
        const float g4v = Lw[GOF + 196 + m];

        const float tx  = (g1v + jf) * invG;
        const float ty  = (g2v + if_) * invG;
        const float tx1 = tx - g3v * 0.5f, tx2 = tx + g3v * 0.5f;
        const float ty1 = ty - g4v * 0.5f, ty2 = ty + g4v * 0.5f;
        const float tarea = (tx2 - tx1) * (ty2 - ty1);

        // ---- 5) IoU argmax over anchors (uniform on all lanes) ----
        int best = 0; float bestIoU = -1.0f;
        float px = 0.f, py = 0.f, pw = 0.f, ph = 0.f;
        #pragma unroll
        for (int a = 0; a < 3; a++) {
            const float c1 = Lw[(5 * a + 1) * GG + m];
            const float c2 = Lw[(5 * a + 2) * GG + m];
            const float c3 = Lw[(5 * a + 3) * GG + m];
            const float c4 = Lw[(5 * a + 4) * GG + m];
            const float ax  = (c1 + jf) * invG;
            const float ay  = (c2 + if_) * invG;
            const float ax1 = ax - c3 * 0.5f, ax2 = ax + c3 * 0.5f;
            const float ay1 = ay - c4 * 0.5f, ay2 = ay + c4 * 0.5f;
            float iw = fminf(ax2, tx2) - fmaxf(ax1, tx1); iw = fmaxf(iw, 0.0f);
            float ih = fminf(ay2, ty2) - fmaxf(ay1, ty1); ih = fmaxf(ih, 0.0f);
            const float inter = iw * ih;
            const float uni   = (ax2 - ax1) * (ay2 - ay1) + tarea - inter;
            const float iou   = inter / (uni + 1e-9f);
            if (iou > bestIoU) { bestIoU = iou; best = a; px = c1; py = c2; pw = c3; ph = c4; }
        }

        // ---- 6) prob_loss: 3x -log(1-p) + best-channel correction ----
        float s = 0.0f;
        if (lane < GG) {
            const float p0 = p[0];                   // pr[lane], still in reg
            const float p1 = Lw[5 * GG  + lane];
            const float p2 = Lw[10 * GG + lane];
            const float l0 = __logf(1.0f - p0);
            const float l1 = __logf(1.0f - p1);
            const float l2 = __logf(1.0f - p2);
            s = -(l0 + l1 + l2);
            const float pbv  = (best == 0) ? p0 : (best == 1) ? p1 : p2;
            const float l1pb = (best == 0) ? l0 : (best == 1) ? l1 : l2;
            s -= t * (__logf(pbv) - l1pb);
        }
        acc += s * invN49;

        // ---- 7) coord + size: 8 logs packed into ONE v_log_f32 on lanes 0-7.
        //         lanes: 0:px 1:1-px 2:py 3:1-py 4:pw 5:g3 6:ph 7:g4 ----
        const float s0  = (lane < 4) ? ((lane < 2) ? px : py)
                                     : ((lane < 6) ? pw : ph);
        const float s1  = (lane < 4) ? (1.0f - s0)
                                     : ((lane < 6) ? g3v : g4v);
        const float la  = (lane & 1) ? s1 : s0;      // >0 on every lane
        const float Lv  = __logf(la);
        const float Lx  = __shfl_xor(Lv, 1);
        float contrib = 0.0f;
        if (lane < 4) {
            const float w = (lane < 2) ? ((lane & 1) ? 1.0f - g1v : g1v)
                                       : ((lane & 1) ? 1.0f - g2v : g2v);
            contrib = -w * Lv;                        // coord BCE terms
        } else if (lane == 4 || lane == 6) {
            contrib = fabsf(Lv - Lx);                 // size log-L1 terms
        }
        acc += contrib;

        // ---- 8) CE mean on lane 5: lse = mx + log(1 + exp(-|x0-x1|)) ----
        if (lane == 5) {
            const float mx  = fmaxf(x0, x1);
            const float lse = mx + __logf(1.0f + __expf(-fabsf(x0 - x1)));
            const float lp  = ((cl == 1) ? x0 : x1) - lse;
            acc -= lp * invN;
        }
    }

    // ---- block reduction, one atomic per block ----
    #pragma unroll
    for (int off = 32; off; off >>= 1) acc += __shfl_xor(acc, off);
    __shared__ float wsum[4];
    if (lane == 0) wsum[wslot] = acc;
    __syncthreads();
    if (threadIdx.x == 0) {
        atomicAdd(out, wsum[0] + wsum[1] + wsum[2] + wsum[3]);
    }
}

extern "C" void kernel_launch(void* const* d_in, const int* in_sizes, int n_in,
                              void* d_out, int out_size, void* d_ws, size_t ws_size,
                              hipStream_t stream) {
    const float* bbox_p = (const float*)d_in[0];   // (N,15,7,7)
    const float* cls_p  = (const float*)d_in[1];   // (N,2)
    const float* bbox_g = (const float*)d_in[2];   // (N,5,7,7)
    const int*   cls_l  = (const int*)d_in[3];     // (N,)
    float* out = (float*)d_out;
    const int N = in_sizes[3];

    hipLaunchKernelGGL(zero_kernel, dim3(1), dim3(64), 0, stream, out);
    // 2048 blocks x 4 waves = 8192 waves, 8 samples/wave (grid shape held fixed
    // across rounds to isolate the nt-load variable).
    hipLaunchKernelGGL(loss_kernel, dim3(2048), dim3(256), 0, stream,
                       bbox_p, cls_p, bbox_g, cls_l, out, N);
}